// Round 3
// baseline (189.449 us; speedup 1.0000x reference)
//
#include <hip/hip_runtime.h>

// out[b,h,q,kv] = scores[b,h,q,kv] + bias[offset[q]]
// B=2,H=16,W=2048 -> 65536 rows of 2048 floats. Pure HBM streaming add.
// R3: 4 rows/iter, 8 independent float4 loads in flight, nontemporal.

typedef float f32x4 __attribute__((ext_vector_type(4)));

// Fast path: W == 2048, block = 256 -> vec_per_row (512) == 2*blockDim.
__global__ __launch_bounds__(256) void bias_bcast_add_fast(
    const f32x4* __restrict__ scores,
    const float* __restrict__ bias,
    const int*   __restrict__ offset,
    f32x4*       __restrict__ out,
    int rows, int W) {
    const int vpr = W >> 2;                       // 512 float4 per row
    const int j  = threadIdx.x;
    const int j2 = j + blockDim.x;
    for (int row = (blockIdx.x << 2); row < rows; row += (gridDim.x << 2)) {
        const float b0 = bias[offset[(row + 0) & (W - 1)]];
        const float b1 = bias[offset[(row + 1) & (W - 1)]];
        const float b2 = bias[offset[(row + 2) & (W - 1)]];
        const float b3 = bias[offset[(row + 3) & (W - 1)]];
        const f32x4* s = scores + (size_t)row * vpr;
        f32x4*       d = out    + (size_t)row * vpr;
        // 8 independent 16B loads in flight per thread before any store.
        f32x4 v00 = __builtin_nontemporal_load(s + 0 * vpr + j);
        f32x4 v01 = __builtin_nontemporal_load(s + 0 * vpr + j2);
        f32x4 v10 = __builtin_nontemporal_load(s + 1 * vpr + j);
        f32x4 v11 = __builtin_nontemporal_load(s + 1 * vpr + j2);
        f32x4 v20 = __builtin_nontemporal_load(s + 2 * vpr + j);
        f32x4 v21 = __builtin_nontemporal_load(s + 2 * vpr + j2);
        f32x4 v30 = __builtin_nontemporal_load(s + 3 * vpr + j);
        f32x4 v31 = __builtin_nontemporal_load(s + 3 * vpr + j2);
        v00 += b0; v01 += b0; v10 += b1; v11 += b1;
        v20 += b2; v21 += b2; v30 += b3; v31 += b3;
        __builtin_nontemporal_store(v00, d + 0 * vpr + j);
        __builtin_nontemporal_store(v01, d + 0 * vpr + j2);
        __builtin_nontemporal_store(v10, d + 1 * vpr + j);
        __builtin_nontemporal_store(v11, d + 1 * vpr + j2);
        __builtin_nontemporal_store(v20, d + 2 * vpr + j);
        __builtin_nontemporal_store(v21, d + 2 * vpr + j2);
        __builtin_nontemporal_store(v30, d + 3 * vpr + j);
        __builtin_nontemporal_store(v31, d + 3 * vpr + j2);
    }
}

// Generic fallback (any W divisible by 4).
__global__ __launch_bounds__(256) void bias_bcast_add_generic(
    const f32x4* __restrict__ scores,
    const float* __restrict__ bias,
    const int*   __restrict__ offset,
    f32x4*       __restrict__ out,
    int rows, int W) {
    const int vpr = W >> 2;
    for (int row = blockIdx.x; row < rows; row += gridDim.x) {
        const int q = row % W;
        const float bq = bias[offset[q]];
        const f32x4* s = scores + (size_t)row * vpr;
        f32x4*       d = out    + (size_t)row * vpr;
        for (int jj = threadIdx.x; jj < vpr; jj += blockDim.x) {
            f32x4 v = __builtin_nontemporal_load(s + jj);
            v += bq;
            __builtin_nontemporal_store(v, d + jj);
        }
    }
}

extern "C" void kernel_launch(void* const* d_in, const int* in_sizes, int n_in,
                              void* d_out, int out_size, void* d_ws, size_t ws_size,
                              hipStream_t stream) {
    const float* scores = (const float*)d_in[0];
    const float* bias   = (const float*)d_in[1];
    const int*   offset = (const int*)d_in[2];
    float* out = (float*)d_out;

    const int W = in_sizes[1];            // 2048
    const int rows = (int)(out_size / W); // 65536

    const int block = 256;
    if (W == 2048 && rows % 4 == 0) {
        const int grid = 2048;            // 8 blocks/CU, 4 rows/iter, 8 sweeps
        bias_bcast_add_fast<<<grid, block, 0, stream>>>(
            (const f32x4*)scores, bias, offset, (f32x4*)out, rows, W);
    } else {
        const int grid = 2048;
        bias_bcast_add_generic<<<grid, block, 0, stream>>>(
            (const f32x4*)scores, bias, offset, (f32x4*)out, rows, W);
    }
}

// Round 4
// 179.349 us; speedup vs baseline: 1.0563x; 1.0563x over previous
//
#include <hip/hip_runtime.h>

// out[b,h,q,kv] = scores[b,h,q,kv] + bias[offset[q]]
// B=2,H=16,W=2048 -> 65536 rows of 2048 floats. Pure HBM streaming add.
// R4 = revert to R2 (best: 179.3 us, 5.99 TB/s = 95% of copy ceiling).
// R3's 8-deep MLP regressed (burstier read/write phasing); 4-deep is optimal.

typedef float f32x4 __attribute__((ext_vector_type(4)));

// Fast path: W == 2048, block = 256 -> vec_per_row (512) == 2*blockDim.
__global__ __launch_bounds__(256) void bias_bcast_add_fast(
    const f32x4* __restrict__ scores,
    const float* __restrict__ bias,
    const int*   __restrict__ offset,
    f32x4*       __restrict__ out,
    int rows, int W) {
    const int vpr = W >> 2;                       // 512 float4 per row
    const int j  = threadIdx.x;
    const int j2 = j + blockDim.x;
    for (int row = (blockIdx.x << 1); row < rows; row += (gridDim.x << 1)) {
        const float b0 = bias[offset[row & (W - 1)]];
        const float b1 = bias[offset[(row + 1) & (W - 1)]];
        const f32x4* s = scores + (size_t)row * vpr;
        f32x4*       d = out    + (size_t)row * vpr;
        // 4 independent 16B loads in flight per thread before any store.
        f32x4 v00 = __builtin_nontemporal_load(s + j);
        f32x4 v01 = __builtin_nontemporal_load(s + j2);
        f32x4 v10 = __builtin_nontemporal_load(s + vpr + j);
        f32x4 v11 = __builtin_nontemporal_load(s + vpr + j2);
        v00 += b0; v01 += b0; v10 += b1; v11 += b1;
        __builtin_nontemporal_store(v00, d + j);
        __builtin_nontemporal_store(v01, d + j2);
        __builtin_nontemporal_store(v10, d + vpr + j);
        __builtin_nontemporal_store(v11, d + vpr + j2);
    }
}

// Generic fallback (any W divisible by 4).
__global__ __launch_bounds__(256) void bias_bcast_add_generic(
    const f32x4* __restrict__ scores,
    const float* __restrict__ bias,
    const int*   __restrict__ offset,
    f32x4*       __restrict__ out,
    int rows, int W) {
    const int vpr = W >> 2;
    for (int row = blockIdx.x; row < rows; row += gridDim.x) {
        const int q = row % W;
        const float bq = bias[offset[q]];
        const f32x4* s = scores + (size_t)row * vpr;
        f32x4*       d = out    + (size_t)row * vpr;
        for (int jj = threadIdx.x; jj < vpr; jj += blockDim.x) {
            f32x4 v = __builtin_nontemporal_load(s + jj);
            v += bq;
            __builtin_nontemporal_store(v, d + jj);
        }
    }
}

extern "C" void kernel_launch(void* const* d_in, const int* in_sizes, int n_in,
                              void* d_out, int out_size, void* d_ws, size_t ws_size,
                              hipStream_t stream) {
    const float* scores = (const float*)d_in[0];
    const float* bias   = (const float*)d_in[1];
    const int*   offset = (const int*)d_in[2];
    float* out = (float*)d_out;

    const int W = in_sizes[1];            // 2048
    const int rows = (int)(out_size / W); // 65536

    const int block = 256;
    const int grid = 2048;                // 32 waves/CU on 256 CUs
    if (W == 2048 && rows % 2 == 0) {
        bias_bcast_add_fast<<<grid, block, 0, stream>>>(
            (const f32x4*)scores, bias, offset, (f32x4*)out, rows, W);
    } else {
        bias_bcast_add_generic<<<grid, block, 0, stream>>>(
            (const f32x4*)scores, bias, offset, (f32x4*)out, rows, W);
    }
}